// Round 1
// baseline (597.524 us; speedup 1.0000x reference)
//
#include <hip/hip_runtime.h>
#include <hip/hip_bf16.h>

#define HID 16

// ---------------- kernels ----------------

__global__ void k_zero(float* __restrict__ p, int n) {
    int i = blockIdx.x * blockDim.x + threadIdx.x;
    if (i < n) p[i] = 0.0f;
}

// agg[dst[e]] += val[src[e]]  (scalar per edge)
__global__ void k_scatter_scalar(const float* __restrict__ val,
                                 const int* __restrict__ src,
                                 const int* __restrict__ dst,
                                 float* __restrict__ agg, int E) {
    int e = blockIdx.x * blockDim.x + threadIdx.x;
    if (e < E) {
        unsafeAtomicAdd(agg + dst[e], val[src[e]]);
    }
}

// z = relu(aggx*w_rel + b + x*w_root);  t = z @ proc_w_rel
__global__ void k_encode(const float* __restrict__ x, const float* __restrict__ aggx,
                         const float* __restrict__ w_rel, const float* __restrict__ w_root,
                         const float* __restrict__ b, const float* __restrict__ pwrel,
                         float* __restrict__ z, float* __restrict__ t, int N) {
    __shared__ float sW[HID * HID];
    __shared__ float swr[HID], swo[HID], sb[HID];
    if (threadIdx.x < HID * HID) sW[threadIdx.x] = pwrel[threadIdx.x];
    if (threadIdx.x < HID) {
        swr[threadIdx.x] = w_rel[threadIdx.x];
        swo[threadIdx.x] = w_root[threadIdx.x];
        sb[threadIdx.x]  = b[threadIdx.x];
    }
    __syncthreads();
    int i = blockIdx.x * blockDim.x + threadIdx.x;
    if (i >= N) return;
    float a = aggx[i], xi = x[i];
    float zi[HID];
#pragma unroll
    for (int h = 0; h < HID; h++)
        zi[h] = fmaxf(fmaf(a, swr[h], fmaf(xi, swo[h], sb[h])), 0.0f);
#pragma unroll
    for (int h = 0; h < HID; h++) z[(size_t)i * HID + h] = zi[h];
#pragma unroll
    for (int h = 0; h < HID; h++) {
        float acc = 0.0f;
#pragma unroll
        for (int k = 0; k < HID; k++) acc = fmaf(zi[k], sW[k * HID + h], acc);
        t[(size_t)i * HID + h] = acc;
    }
}

// aggT[dst[e]*16+h] += t[src[e]*16+h] ; one thread per (edge,h)
__global__ void k_scatter_vec(const float* __restrict__ t,
                              const int* __restrict__ src,
                              const int* __restrict__ dst,
                              float* __restrict__ agg, int total) {
    int idx = blockIdx.x * blockDim.x + threadIdx.x;
    if (idx < total) {
        int e = idx >> 4;
        int h = idx & 15;
        unsafeAtomicAdd(agg + (size_t)dst[e] * HID + h, t[(size_t)src[e] * HID + h]);
    }
}

// z2 = aggT + pb + z @ pwroot ; s2 = z2 . dwrel ; r2 = z2 . dwroot + db
__global__ void k_process(const float* __restrict__ z, const float* __restrict__ aggT,
                          const float* __restrict__ pwroot, const float* __restrict__ pb,
                          const float* __restrict__ dwrel, const float* __restrict__ dwroot,
                          const float* __restrict__ db,
                          float* __restrict__ s2, float* __restrict__ r2, int N) {
    __shared__ float sW[HID * HID];
    __shared__ float spb[HID], sdr[HID], sdo[HID];
    __shared__ float sdb;
    if (threadIdx.x < HID * HID) sW[threadIdx.x] = pwroot[threadIdx.x];
    if (threadIdx.x < HID) {
        spb[threadIdx.x] = pb[threadIdx.x];
        sdr[threadIdx.x] = dwrel[threadIdx.x];
        sdo[threadIdx.x] = dwroot[threadIdx.x];
    }
    if (threadIdx.x == 0) sdb = db[0];
    __syncthreads();
    int i = blockIdx.x * blockDim.x + threadIdx.x;
    if (i >= N) return;
    float zi[HID];
#pragma unroll
    for (int k = 0; k < HID; k++) zi[k] = z[(size_t)i * HID + k];
    float ssum = 0.0f, rsum = sdb;
#pragma unroll
    for (int h = 0; h < HID; h++) {
        float acc = aggT[(size_t)i * HID + h] + spb[h];
#pragma unroll
        for (int k = 0; k < HID; k++) acc = fmaf(zi[k], sW[k * HID + h], acc);
        ssum = fmaf(acc, sdr[h], ssum);
        rsum = fmaf(acc, sdo[h], rsum);
    }
    s2[i] = ssum;
    r2[i] = rsum;
}

__global__ void k_final(const float* __restrict__ aggS, const float* __restrict__ r2,
                        float* __restrict__ out, int N) {
    int i = blockIdx.x * blockDim.x + threadIdx.x;
    if (i < N) out[i] = fmaxf(aggS[i] + r2[i], 0.0f);
}

// ---------------- launch ----------------

extern "C" void kernel_launch(void* const* d_in, const int* in_sizes, int n_in,
                              void* d_out, int out_size, void* d_ws, size_t ws_size,
                              hipStream_t stream) {
    const float* x         = (const float*)d_in[0];
    const int*   ei        = (const int*)d_in[1];
    const float* enc_wrel  = (const float*)d_in[2];
    const float* enc_wroot = (const float*)d_in[3];
    const float* enc_b     = (const float*)d_in[4];
    const float* proc_wrel = (const float*)d_in[5];
    const float* proc_wroot= (const float*)d_in[6];
    const float* proc_b    = (const float*)d_in[7];
    const float* dec_wrel  = (const float*)d_in[8];
    const float* dec_wroot = (const float*)d_in[9];
    const float* dec_b     = (const float*)d_in[10];
    float* out = (float*)d_out;

    const int N = in_sizes[0];        // 100000 (x is [N,1])
    const int E = in_sizes[1] / 2;    // edge_index is [2, E]
    const int* src = ei;
    const int* dst = ei + E;

    // workspace layout (floats):
    // [0,N)       aggx
    // [N,17N)     aggT  (16N)
    // [17N,18N)   aggS
    // [18N,34N)   z
    // [34N,50N)   t
    // [50N,51N)   s2
    // [51N,52N)   r2
    float* ws   = (float*)d_ws;
    float* aggx = ws;
    float* aggT = ws + (size_t)N;
    float* aggS = ws + (size_t)17 * N;
    float* z    = ws + (size_t)18 * N;
    float* t    = ws + (size_t)34 * N;
    float* s2   = ws + (size_t)50 * N;
    float* r2   = ws + (size_t)51 * N;

    const int B = 256;
    int zeroN = 18 * N;  // aggx + aggT + aggS are contiguous

    hipLaunchKernelGGL(k_zero, dim3((zeroN + B - 1) / B), dim3(B), 0, stream, aggx, zeroN);

    // layer 1: scalar aggregation of x
    hipLaunchKernelGGL(k_scatter_scalar, dim3((E + B - 1) / B), dim3(B), 0, stream,
                       x, src, dst, aggx, E);

    // encode + pre-transform t = z @ proc_w_rel
    hipLaunchKernelGGL(k_encode, dim3((N + B - 1) / B), dim3(B), 0, stream,
                       x, aggx, enc_wrel, enc_wroot, enc_b, proc_wrel, z, t, N);

    // layer 2 aggregation: 16 floats per edge
    int total = E * HID;
    hipLaunchKernelGGL(k_scatter_vec, dim3((total + B - 1) / B), dim3(B), 0, stream,
                       t, src, dst, aggT, total);

    // process + decoder per-node precompute (s2, r2)
    hipLaunchKernelGGL(k_process, dim3((N + B - 1) / B), dim3(B), 0, stream,
                       z, aggT, proc_wroot, proc_b, dec_wrel, dec_wroot, dec_b, s2, r2, N);

    // layer 3 aggregation: scalar
    hipLaunchKernelGGL(k_scatter_scalar, dim3((E + B - 1) / B), dim3(B), 0, stream,
                       s2, src, dst, aggS, E);

    hipLaunchKernelGGL(k_final, dim3((N + B - 1) / B), dim3(B), 0, stream, aggS, r2, out, N);
}

// Round 2
// 266.268 us; speedup vs baseline: 2.2441x; 2.2441x over previous
//
#include <hip/hip_runtime.h>
#include <hip/hip_bf16.h>

#define HID 16
#define RANGE_BITS 13
#define RANGE (1 << RANGE_BITS)          // 8192 nodes per range
#define SRC_BITS 17                      // N=100000 < 2^17
#define SRC_MASK ((1u << SRC_BITS) - 1)
#define NR_MAX 16
#define PART_BLOCK 256
#define PART_K 16
#define TILE (PART_BLOCK * PART_K)       // 4096 edges per tile
#define SCAT_BLOCK 1024

// ---------------- init: zero the range cursors ----------------
__global__ void k_init(int* __restrict__ gcur, int nr) {
    int i = threadIdx.x;
    if (i < nr) gcur[i] = 0;
}

// ---------------- partition edges by dst range, packed (dloc<<17)|src --------
__global__ void k_partition(const int* __restrict__ src, const int* __restrict__ dst,
                            unsigned* __restrict__ buckets, int* __restrict__ gcur,
                            int E, int nr, int cap, int ntiles) {
    __shared__ int cnt[NR_MAX];
    __shared__ int base[NR_MAX];
    for (int tile = blockIdx.x; tile < ntiles; tile += gridDim.x) {
        int tb = tile * TILE;
        if (threadIdx.x < nr) cnt[threadIdx.x] = 0;
        __syncthreads();
        int rr[PART_K]; int rk[PART_K]; unsigned pk[PART_K];
#pragma unroll
        for (int k = 0; k < PART_K; k++) {
            int e = tb + k * PART_BLOCK + threadIdx.x;
            if (e < E) {
                int d = dst[e];
                int s = src[e];
                int r = d >> RANGE_BITS;
                rr[k] = r;
                pk[k] = ((unsigned)(d & (RANGE - 1)) << SRC_BITS) | (unsigned)s;
                rk[k] = atomicAdd(&cnt[r], 1);
            } else {
                rr[k] = -1; rk[k] = 0; pk[k] = 0;
            }
        }
        __syncthreads();
        if (threadIdx.x < nr && cnt[threadIdx.x] > 0)
            base[threadIdx.x] = atomicAdd(&gcur[threadIdx.x], cnt[threadIdx.x]);
        __syncthreads();
#pragma unroll
        for (int k = 0; k < PART_K; k++) {
            if (rr[k] >= 0) {
                int idx = base[rr[k]] + rk[k];
                if (idx < cap)  // capacity guard (cap has >>100 sigma slack)
                    buckets[(size_t)rr[k] * cap + idx] = pk[k];
            }
        }
        __syncthreads();
    }
}

// ---------------- scalar binned scatter: LDS bins -> private partials --------
__global__ void __launch_bounds__(SCAT_BLOCK)
k_scatter_f1(const unsigned* __restrict__ buckets, const int* __restrict__ gcur,
             const float* __restrict__ val, float* __restrict__ partial,
             int nc, int cap) {
    __shared__ float bins[RANGE];        // 32 KB
    int r = blockIdx.x / nc, c = blockIdx.x % nc;
    int cnt = gcur[r];
    int seg = (cnt + nc - 1) / nc;
    int b0 = c * seg;
    int b1 = min(cnt, b0 + seg);
    for (int i = threadIdx.x; i < RANGE; i += SCAT_BLOCK) bins[i] = 0.f;
    __syncthreads();
    const unsigned* bk = buckets + (size_t)r * cap;
    for (int e = b0 + threadIdx.x; e < b1; e += SCAT_BLOCK) {
        unsigned pk = bk[e];
        atomicAdd(&bins[pk >> SRC_BITS], val[pk & SRC_MASK]);
    }
    __syncthreads();
    float* p = partial + (size_t)blockIdx.x * RANGE;
    for (int i = threadIdx.x; i < RANGE; i += SCAT_BLOCK) p[i] = bins[i];
}

__global__ void k_reduce_f1(const float* __restrict__ partial, float* __restrict__ out,
                            int nc, int N) {
    int n = blockIdx.x * blockDim.x + threadIdx.x;
    if (n >= N) return;
    int r = n >> RANGE_BITS, dl = n & (RANGE - 1);
    float s = 0.f;
    for (int c = 0; c < nc; c++) s += partial[((size_t)(r * nc + c)) * RANGE + dl];
    out[n] = s;
}

// ---------------- float2 binned scatter (fused a,b aggregation) --------------
__global__ void __launch_bounds__(SCAT_BLOCK)
k_scatter_f2(const unsigned* __restrict__ buckets, const int* __restrict__ gcur,
             const float* __restrict__ val2, float* __restrict__ partial,
             int nc, int cap) {
    __shared__ float bins[2 * RANGE];    // 64 KB
    int r = blockIdx.x / nc, c = blockIdx.x % nc;
    int cnt = gcur[r];
    int seg = (cnt + nc - 1) / nc;
    int b0 = c * seg;
    int b1 = min(cnt, b0 + seg);
    for (int i = threadIdx.x; i < 2 * RANGE; i += SCAT_BLOCK) bins[i] = 0.f;
    __syncthreads();
    const unsigned* bk = buckets + (size_t)r * cap;
    const float2* v2 = (const float2*)val2;
    for (int e = b0 + threadIdx.x; e < b1; e += SCAT_BLOCK) {
        unsigned pk = bk[e];
        float2 v = v2[pk & SRC_MASK];
        int dl = (int)(pk >> SRC_BITS);
        atomicAdd(&bins[2 * dl], v.x);
        atomicAdd(&bins[2 * dl + 1], v.y);
    }
    __syncthreads();
    float2* p = (float2*)partial + (size_t)blockIdx.x * RANGE;
    const float2* b2 = (const float2*)bins;
    for (int i = threadIdx.x; i < RANGE; i += SCAT_BLOCK) p[i] = b2[i];
}

__global__ void k_reduce_f2(const float* __restrict__ partial, float* __restrict__ D2,
                            int nc, int N) {
    int n = blockIdx.x * blockDim.x + threadIdx.x;
    if (n >= N) return;
    int r = n >> RANGE_BITS, dl = n & (RANGE - 1);
    const float2* p2 = (const float2*)partial;
    float sx = 0.f, sy = 0.f;
    for (int c = 0; c < nc; c++) {
        float2 v = p2[((size_t)(r * nc + c)) * RANGE + dl];
        sx += v.x; sy += v.y;
    }
    ((float2*)D2)[n] = make_float2(sx, sy);
}

// ---------------- encode: z1 in regs, emit 4 collapsed scalars ---------------
// u1 = Wp_rel·wd_rel, u2 = Wp_rel·wd_root, v1 = Wp_root·wd_rel, v2 = Wp_root·wd_root
__global__ void k_encode(const float* __restrict__ x, const float* __restrict__ D1,
                         const float* __restrict__ ewrel, const float* __restrict__ ewroot,
                         const float* __restrict__ eb,
                         const float* __restrict__ pwrel, const float* __restrict__ pwroot,
                         const float* __restrict__ dwrel, const float* __restrict__ dwroot,
                         float* __restrict__ SAB, float* __restrict__ G1,
                         float* __restrict__ G2, int N) {
    __shared__ float su1[HID], su2[HID], sv1[HID], sv2[HID];
    __shared__ float swr[HID], swo[HID], sbb[HID];
    int t = threadIdx.x;
    if (t < 64) {
        int k = t & 15, w = t >> 4;
        const float* M  = (w < 2) ? pwrel : pwroot;
        const float* vv = ((w & 1) == 0) ? dwrel : dwroot;
        float acc = 0.f;
        for (int h = 0; h < HID; h++) acc += M[k * HID + h] * vv[h];
        if (w == 0) su1[k] = acc;
        else if (w == 1) su2[k] = acc;
        else if (w == 2) sv1[k] = acc;
        else sv2[k] = acc;
    }
    if (t < HID) { swr[t] = ewrel[t]; swo[t] = ewroot[t]; sbb[t] = eb[t]; }
    __syncthreads();
    int i = blockIdx.x * blockDim.x + t;
    if (i >= N) return;
    float a1 = D1[i], xi = x[i];
    float sa = 0.f, sb = 0.f, g1 = 0.f, g2 = 0.f;
#pragma unroll
    for (int h = 0; h < HID; h++) {
        float z = fmaxf(fmaf(a1, swr[h], fmaf(xi, swo[h], sbb[h])), 0.f);
        sa = fmaf(z, su1[h], sa);
        sb = fmaf(z, su2[h], sb);
        g1 = fmaf(z, sv1[h], g1);
        g2 = fmaf(z, sv2[h], g2);
    }
    SAB[2 * i] = sa; SAB[2 * i + 1] = sb; G1[i] = g1; G2[i] = g2;
}

// ---------------- mid: beta (to scatter) and root term R ---------------------
__global__ void k_mid(const float* __restrict__ D2, const float* __restrict__ G1,
                      const float* __restrict__ G2,
                      const float* __restrict__ pb, const float* __restrict__ dwrel,
                      const float* __restrict__ dwroot, const float* __restrict__ db,
                      float* __restrict__ BETA, float* __restrict__ R, int N) {
    __shared__ float sc1, sc2, sbd;
    if (threadIdx.x == 0) {
        float c1 = 0.f, c2 = 0.f;
        for (int h = 0; h < HID; h++) { c1 += pb[h] * dwrel[h]; c2 += pb[h] * dwroot[h]; }
        sc1 = c1; sc2 = c2; sbd = db[0];
    }
    __syncthreads();
    int i = blockIdx.x * blockDim.x + threadIdx.x;
    if (i >= N) return;
    float2 d2 = ((const float2*)D2)[i];
    BETA[i] = d2.x + G1[i] + sc1;
    R[i]    = d2.y + G2[i] + sc2 + sbd;
}

__global__ void k_final(const float* __restrict__ D3, const float* __restrict__ R,
                        float* __restrict__ out, int N) {
    int i = blockIdx.x * blockDim.x + threadIdx.x;
    if (i < N) out[i] = fmaxf(D3[i] + R[i], 0.f);
}

// ---------------- launch ----------------
extern "C" void kernel_launch(void* const* d_in, const int* in_sizes, int n_in,
                              void* d_out, int out_size, void* d_ws, size_t ws_size,
                              hipStream_t stream) {
    const float* x      = (const float*)d_in[0];
    const int*   ei     = (const int*)d_in[1];
    const float* ewrel  = (const float*)d_in[2];
    const float* ewroot = (const float*)d_in[3];
    const float* eb     = (const float*)d_in[4];
    const float* pwrel  = (const float*)d_in[5];
    const float* pwroot = (const float*)d_in[6];
    const float* pb     = (const float*)d_in[7];
    const float* dwrel  = (const float*)d_in[8];
    const float* dwroot = (const float*)d_in[9];
    const float* db     = (const float*)d_in[10];
    float* out = (float*)d_out;

    const int N = in_sizes[0];
    const int E = in_sizes[1] / 2;
    const int* src = ei;
    const int* dst = ei + E;

    const int nr = (N + RANGE - 1) >> RANGE_BITS;        // 13
    int cap = E / nr + 8000;
    cap = (cap + 1) & ~1;                                 // even, keeps float2 alignment

    // workspace layout (4-byte words)
    size_t words = ws_size / 4;
    size_t off = 0;
    int* gcur = (int*)d_ws + off;            off += 64;
    unsigned* buckets = (unsigned*)d_ws + off; off += (size_t)nr * cap;
    float* SAB  = (float*)d_ws + off;        off += (size_t)2 * N;
    float* G1   = (float*)d_ws + off;        off += N;
    float* G2   = (float*)d_ws + off;        off += N;
    float* BETA = (float*)d_ws + off;        off += N;
    float* R    = (float*)d_ws + off;        off += N;
    float* D1   = (float*)d_ws + off;        off += N;
    float* D2   = (float*)d_ws + off;        off += (size_t)2 * N;
    float* D3   = (float*)d_ws + off;        off += N;
    // partial buffer: shared between passes; f2 pass needs nc2*nr*RANGE*2 words,
    // f1 passes use nc1*nr*RANGE words with nc1 = 2*nc2 (same size).
    int nc2 = 10;
    while (nc2 > 1 && off + (size_t)2 * nc2 * nr * RANGE > words) nc2--;
    int nc1 = 2 * nc2;
    float* partial = (float*)d_ws + off;

    const int ntiles = (E + TILE - 1) / TILE;
    const int nodeBlocks = (N + 255) / 256;

    hipLaunchKernelGGL(k_init, dim3(1), dim3(64), 0, stream, gcur, nr);
    hipLaunchKernelGGL(k_partition, dim3(256), dim3(PART_BLOCK), 0, stream,
                       src, dst, buckets, gcur, E, nr, cap, ntiles);

    // pass 1: D1 = scatter(x)
    hipLaunchKernelGGL(k_scatter_f1, dim3(nr * nc1), dim3(SCAT_BLOCK), 0, stream,
                       buckets, gcur, x, partial, nc1, cap);
    hipLaunchKernelGGL(k_reduce_f1, dim3(nodeBlocks), dim3(256), 0, stream,
                       partial, D1, nc1, N);

    // encode: z1 in regs -> SAB (a,b interleaved), G1, G2
    hipLaunchKernelGGL(k_encode, dim3(nodeBlocks), dim3(256), 0, stream,
                       x, D1, ewrel, ewroot, eb, pwrel, pwroot, dwrel, dwroot,
                       SAB, G1, G2, N);

    // pass 2: D2 = scatter(float2(a,b))
    hipLaunchKernelGGL(k_scatter_f2, dim3(nr * nc2), dim3(SCAT_BLOCK), 0, stream,
                       buckets, gcur, SAB, partial, nc2, cap);
    hipLaunchKernelGGL(k_reduce_f2, dim3(nodeBlocks), dim3(256), 0, stream,
                       partial, D2, nc2, N);

    // mid: BETA = D2a + G1 + c1 ; R = D2b + G2 + c2 + bd
    hipLaunchKernelGGL(k_mid, dim3(nodeBlocks), dim3(256), 0, stream,
                       D2, G1, G2, pb, dwrel, dwroot, db, BETA, R, N);

    // pass 3: D3 = scatter(BETA)
    hipLaunchKernelGGL(k_scatter_f1, dim3(nr * nc1), dim3(SCAT_BLOCK), 0, stream,
                       buckets, gcur, BETA, partial, nc1, cap);
    hipLaunchKernelGGL(k_reduce_f1, dim3(nodeBlocks), dim3(256), 0, stream,
                       partial, D3, nc1, N);

    hipLaunchKernelGGL(k_final, dim3(nodeBlocks), dim3(256), 0, stream, D3, R, out, N);
}

// Round 3
// 232.126 us; speedup vs baseline: 2.5741x; 1.1471x over previous
//
#include <hip/hip_runtime.h>
#include <hip/hip_bf16.h>

#define HID 16
#define RANGE_BITS 10
#define RANGE (1 << RANGE_BITS)          // 1024 nodes per range
#define SRC_BITS 17                      // N=100000 < 2^17
#define SRC_MASK ((1u << SRC_BITS) - 1)
#define NR_MAX 128
#define PART_BLOCK 256
#define PART_K 16
#define TILE (PART_BLOCK * PART_K)       // 4096 edges per tile
#define SCAT_BLOCK 256

// ---------------- init: zero the range cursors ----------------
__global__ void k_init(int* __restrict__ gcur) {
    gcur[threadIdx.x] = 0;
}

// ---------------- partition edges by dst range, packed (dloc<<17)|src --------
__global__ void k_partition(const int* __restrict__ src, const int* __restrict__ dst,
                            unsigned* __restrict__ buckets, int* __restrict__ gcur,
                            int E, int nr, int cap, int ntiles) {
    __shared__ int cnt[NR_MAX];
    __shared__ int base[NR_MAX];
    for (int tile = blockIdx.x; tile < ntiles; tile += gridDim.x) {
        int tb = tile * TILE;
        if (threadIdx.x < nr) cnt[threadIdx.x] = 0;
        __syncthreads();
        int rr[PART_K]; int rk[PART_K]; unsigned pk[PART_K];
#pragma unroll
        for (int k = 0; k < PART_K; k++) {
            int e = tb + k * PART_BLOCK + threadIdx.x;
            if (e < E) {
                int d = dst[e];
                int s = src[e];
                int r = d >> RANGE_BITS;
                rr[k] = r;
                pk[k] = ((unsigned)(d & (RANGE - 1)) << SRC_BITS) | (unsigned)s;
                rk[k] = atomicAdd(&cnt[r], 1);
            } else {
                rr[k] = -1; rk[k] = 0; pk[k] = 0;
            }
        }
        __syncthreads();
        if (threadIdx.x < nr && cnt[threadIdx.x] > 0)
            base[threadIdx.x] = atomicAdd(&gcur[threadIdx.x], cnt[threadIdx.x]);
        __syncthreads();
#pragma unroll
        for (int k = 0; k < PART_K; k++) {
            if (rr[k] >= 0) {
                int idx = base[rr[k]] + rk[k];
                if (idx < cap)   // capacity guard (>10 sigma slack)
                    buckets[(size_t)rr[k] * cap + idx] = pk[k];
            }
        }
        __syncthreads();
    }
}

// ---------------- scalar binned scatter: 4KB LDS bins -> private partials ----
__global__ void __launch_bounds__(SCAT_BLOCK)
k_scatter_f1(const unsigned* __restrict__ buckets, const int* __restrict__ gcur,
             const float* __restrict__ val, float* __restrict__ partial,
             int nc, int cap) {
    __shared__ float bins[RANGE];
    int r = blockIdx.x / nc, c = blockIdx.x % nc;
    int cnt = gcur[r];
    int seg = (((cnt + nc - 1) / nc) + 3) & ~3;
    int b0 = c * seg;
    int b1 = min(cnt, b0 + seg);
    for (int i = threadIdx.x; i < RANGE; i += SCAT_BLOCK) bins[i] = 0.f;
    __syncthreads();
    const unsigned* bk = buckets + (size_t)r * cap;
    int e = b0 + (threadIdx.x << 2);
    for (; e + 4 <= b1; e += (SCAT_BLOCK << 2)) {
        uint4 p = *(const uint4*)(bk + e);
        float v0 = val[p.x & SRC_MASK];
        float v1 = val[p.y & SRC_MASK];
        float v2 = val[p.z & SRC_MASK];
        float v3 = val[p.w & SRC_MASK];
        atomicAdd(&bins[p.x >> SRC_BITS], v0);
        atomicAdd(&bins[p.y >> SRC_BITS], v1);
        atomicAdd(&bins[p.z >> SRC_BITS], v2);
        atomicAdd(&bins[p.w >> SRC_BITS], v3);
    }
    int e1 = min(b1, e + 4);
    for (int q = e; q < e1; q++) {
        unsigned pk = bk[q];
        atomicAdd(&bins[pk >> SRC_BITS], val[pk & SRC_MASK]);
    }
    __syncthreads();
    float* p = partial + (size_t)blockIdx.x * RANGE;
    for (int i = threadIdx.x; i < RANGE; i += SCAT_BLOCK) p[i] = bins[i];
}

// ---------------- float2 binned scatter, separate a/b planes -----------------
__global__ void __launch_bounds__(SCAT_BLOCK)
k_scatter_f2(const unsigned* __restrict__ buckets, const int* __restrict__ gcur,
             const float* __restrict__ val2, float* __restrict__ partial,
             int nc, int cap) {
    __shared__ float ba[RANGE];
    __shared__ float bb[RANGE];
    int r = blockIdx.x / nc, c = blockIdx.x % nc;
    int cnt = gcur[r];
    int seg = (((cnt + nc - 1) / nc) + 3) & ~3;
    int b0 = c * seg;
    int b1 = min(cnt, b0 + seg);
    for (int i = threadIdx.x; i < RANGE; i += SCAT_BLOCK) { ba[i] = 0.f; bb[i] = 0.f; }
    __syncthreads();
    const unsigned* bk = buckets + (size_t)r * cap;
    const float2* v2 = (const float2*)val2;
    int e = b0 + (threadIdx.x << 2);
    for (; e + 4 <= b1; e += (SCAT_BLOCK << 2)) {
        uint4 p = *(const uint4*)(bk + e);
        float2 v0 = v2[p.x & SRC_MASK];
        float2 v1 = v2[p.y & SRC_MASK];
        float2 w2 = v2[p.z & SRC_MASK];
        float2 w3 = v2[p.w & SRC_MASK];
        atomicAdd(&ba[p.x >> SRC_BITS], v0.x); atomicAdd(&bb[p.x >> SRC_BITS], v0.y);
        atomicAdd(&ba[p.y >> SRC_BITS], v1.x); atomicAdd(&bb[p.y >> SRC_BITS], v1.y);
        atomicAdd(&ba[p.z >> SRC_BITS], w2.x); atomicAdd(&bb[p.z >> SRC_BITS], w2.y);
        atomicAdd(&ba[p.w >> SRC_BITS], w3.x); atomicAdd(&bb[p.w >> SRC_BITS], w3.y);
    }
    int e1 = min(b1, e + 4);
    for (int q = e; q < e1; q++) {
        unsigned pk = bk[q];
        float2 v = v2[pk & SRC_MASK];
        atomicAdd(&ba[pk >> SRC_BITS], v.x);
        atomicAdd(&bb[pk >> SRC_BITS], v.y);
    }
    __syncthreads();
    float* pa = partial + (size_t)blockIdx.x * 2 * RANGE;
    for (int i = threadIdx.x; i < RANGE; i += SCAT_BLOCK) {
        pa[i] = ba[i];
        pa[RANGE + i] = bb[i];
    }
}

// ---------------- fused reduce(D1) + encode ---------------------------------
// u1 = Wp_rel·wd_rel, u2 = Wp_rel·wd_root, v1 = Wp_root·wd_rel, v2 = Wp_root·wd_root
__global__ void k_encode(const float* __restrict__ x, const float* __restrict__ partial,
                         int nc,
                         const float* __restrict__ ewrel, const float* __restrict__ ewroot,
                         const float* __restrict__ eb,
                         const float* __restrict__ pwrel, const float* __restrict__ pwroot,
                         const float* __restrict__ dwrel, const float* __restrict__ dwroot,
                         float* __restrict__ SAB, float* __restrict__ G1,
                         float* __restrict__ G2, int N) {
    __shared__ float su1[HID], su2[HID], sv1[HID], sv2[HID];
    __shared__ float swr[HID], swo[HID], sbb[HID];
    int t = threadIdx.x;
    if (t < 64) {
        int k = t & 15, w = t >> 4;
        const float* M  = (w < 2) ? pwrel : pwroot;
        const float* vv = ((w & 1) == 0) ? dwrel : dwroot;
        float acc = 0.f;
        for (int h = 0; h < HID; h++) acc += M[k * HID + h] * vv[h];
        if (w == 0) su1[k] = acc;
        else if (w == 1) su2[k] = acc;
        else if (w == 2) sv1[k] = acc;
        else sv2[k] = acc;
    }
    if (t < HID) { swr[t] = ewrel[t]; swo[t] = ewroot[t]; sbb[t] = eb[t]; }
    __syncthreads();
    int i = blockIdx.x * blockDim.x + t;
    if (i >= N) return;
    int r = i >> RANGE_BITS, dl = i & (RANGE - 1);
    float a1 = 0.f;
    for (int c = 0; c < nc; c++)
        a1 += partial[((size_t)(r * nc + c) << RANGE_BITS) + dl];
    float xi = x[i];
    float sa = 0.f, sb = 0.f, g1 = 0.f, g2 = 0.f;
#pragma unroll
    for (int h = 0; h < HID; h++) {
        float z = fmaxf(fmaf(a1, swr[h], fmaf(xi, swo[h], sbb[h])), 0.f);
        sa = fmaf(z, su1[h], sa);
        sb = fmaf(z, su2[h], sb);
        g1 = fmaf(z, sv1[h], g1);
        g2 = fmaf(z, sv2[h], g2);
    }
    SAB[2 * i] = sa; SAB[2 * i + 1] = sb; G1[i] = g1; G2[i] = g2;
}

// ---------------- fused reduce(D2) + mid ------------------------------------
__global__ void k_mid(const float* __restrict__ partial, int nc,
                      const float* __restrict__ G1, const float* __restrict__ G2,
                      const float* __restrict__ pb, const float* __restrict__ dwrel,
                      const float* __restrict__ dwroot, const float* __restrict__ db,
                      float* __restrict__ BETA, float* __restrict__ R, int N) {
    __shared__ float sc1, sc2, sbd;
    if (threadIdx.x == 0) {
        float c1 = 0.f, c2 = 0.f;
        for (int h = 0; h < HID; h++) { c1 += pb[h] * dwrel[h]; c2 += pb[h] * dwroot[h]; }
        sc1 = c1; sc2 = c2; sbd = db[0];
    }
    __syncthreads();
    int i = blockIdx.x * blockDim.x + threadIdx.x;
    if (i >= N) return;
    int r = i >> RANGE_BITS, dl = i & (RANGE - 1);
    float sa = 0.f, sb = 0.f;
    for (int c = 0; c < nc; c++) {
        const float* pa = partial + ((size_t)(r * nc + c) * 2 << RANGE_BITS);
        sa += pa[dl];
        sb += pa[RANGE + dl];
    }
    BETA[i] = sa + G1[i] + sc1;
    R[i]    = sb + G2[i] + sc2 + sbd;
}

// ---------------- fused reduce(D3) + final ----------------------------------
__global__ void k_final(const float* __restrict__ partial, int nc,
                        const float* __restrict__ R,
                        float* __restrict__ out, int N) {
    int i = blockIdx.x * blockDim.x + threadIdx.x;
    if (i >= N) return;
    int r = i >> RANGE_BITS, dl = i & (RANGE - 1);
    float s = 0.f;
    for (int c = 0; c < nc; c++)
        s += partial[((size_t)(r * nc + c) << RANGE_BITS) + dl];
    out[i] = fmaxf(s + R[i], 0.f);
}

// ---------------- launch ----------------
extern "C" void kernel_launch(void* const* d_in, const int* in_sizes, int n_in,
                              void* d_out, int out_size, void* d_ws, size_t ws_size,
                              hipStream_t stream) {
    const float* x      = (const float*)d_in[0];
    const int*   ei     = (const int*)d_in[1];
    const float* ewrel  = (const float*)d_in[2];
    const float* ewroot = (const float*)d_in[3];
    const float* eb     = (const float*)d_in[4];
    const float* pwrel  = (const float*)d_in[5];
    const float* pwroot = (const float*)d_in[6];
    const float* pb     = (const float*)d_in[7];
    const float* dwrel  = (const float*)d_in[8];
    const float* dwroot = (const float*)d_in[9];
    const float* db     = (const float*)d_in[10];
    float* out = (float*)d_out;

    const int N = in_sizes[0];
    const int E = in_sizes[1] / 2;
    const int* src = ei;
    const int* dst = ei + E;

    const int nr = (N + RANGE - 1) >> RANGE_BITS;     // 98
    int cap = E / nr + 2048;
    cap = (cap + 3) & ~3;                              // 16B-aligned rows for uint4

    // workspace layout (4-byte words)
    size_t words = ws_size / 4;
    size_t off = 0;
    int* gcur = (int*)d_ws;                    off += NR_MAX;
    unsigned* buckets = (unsigned*)d_ws + off; off += (size_t)nr * cap;
    float* SAB  = (float*)d_ws + off;          off += (size_t)2 * N;
    float* G1   = (float*)d_ws + off;          off += N;
    float* G2   = (float*)d_ws + off;          off += N;
    float* BETA = (float*)d_ws + off;          off += N;
    float* R    = (float*)d_ws + off;          off += N;
    // shared partial buffer: f2 needs nc2*nr*2*RANGE words; f1 uses nc1=2*nc2
    // planes of nr*RANGE words (same footprint).
    int nc2 = 8;
    while (nc2 > 1 && off + ((size_t)nc2 * nr * 2 << RANGE_BITS) > words) nc2--;
    int nc1 = 2 * nc2;
    float* partial = (float*)d_ws + off;

    const int ntiles = (E + TILE - 1) / TILE;
    const int nodeBlocks = (N + 255) / 256;

    hipLaunchKernelGGL(k_init, dim3(1), dim3(NR_MAX), 0, stream, gcur);
    hipLaunchKernelGGL(k_partition, dim3(512), dim3(PART_BLOCK), 0, stream,
                       src, dst, buckets, gcur, E, nr, cap, ntiles);

    // pass 1: scatter(x) -> partials; fused reduce in k_encode
    hipLaunchKernelGGL(k_scatter_f1, dim3(nr * nc1), dim3(SCAT_BLOCK), 0, stream,
                       buckets, gcur, x, partial, nc1, cap);
    hipLaunchKernelGGL(k_encode, dim3(nodeBlocks), dim3(256), 0, stream,
                       x, partial, nc1, ewrel, ewroot, eb, pwrel, pwroot,
                       dwrel, dwroot, SAB, G1, G2, N);

    // pass 2: scatter(float2(a,b)) -> partials; fused reduce in k_mid
    hipLaunchKernelGGL(k_scatter_f2, dim3(nr * nc2), dim3(SCAT_BLOCK), 0, stream,
                       buckets, gcur, SAB, partial, nc2, cap);
    hipLaunchKernelGGL(k_mid, dim3(nodeBlocks), dim3(256), 0, stream,
                       partial, nc2, G1, G2, pb, dwrel, dwroot, db, BETA, R, N);

    // pass 3: scatter(BETA) -> partials; fused reduce in k_final
    hipLaunchKernelGGL(k_scatter_f1, dim3(nr * nc1), dim3(SCAT_BLOCK), 0, stream,
                       buckets, gcur, BETA, partial, nc1, cap);
    hipLaunchKernelGGL(k_final, dim3(nodeBlocks), dim3(256), 0, stream,
                       partial, nc1, R, out, N);
}